// Round 1
// baseline (92.852 us; speedup 1.0000x reference)
//
#include <hip/hip_runtime.h>

#define OUTS 7
#define CC 256
#define HH 56
#define WW 56
#define PX (HH * WW)   // 3136
#define STRIDE 58      // px row stride (even: keeps 16B staging alignment)
#define SPLIT 4        // ROI-list split across sibling blocks (R11: 2->4)
#define MAXROI 96

typedef _Float16 half2_t __attribute__((ext_vector_type(2)));  // trivially copyable

// R11: same R8/R10 structure (LDS-staged packed-fp16 plane, lane=bin,
// chunked-ILP scan, deterministic ROI list), but SPLIT 2 -> 4.
// Rationale: kernel phase is staging-latency-bound, not BW/issue-bound
// (51 MB reads =~ 8 us at BW, yet kernel ~42 us). grid=1024 supplied only
// 4 blocks/CU while the 26 KB LDS footprint admits 6 resident. SPLIT=4
// supplies 8/CU -> 6 resident (24 waves/CU) during staging + a backfill
// round. Duplicate plane reads (102 MB total) are L3-absorbed: the whole
// image tensor is 25.7 MB << 256 MiB Infinity Cache, so HBM FETCH stays
// ~compulsory. Scan stripes 8 -> 16; each ROI-cquad still written once.
__global__ __launch_bounds__(256) void roipool_kernel(
    const float* __restrict__ images, const float* __restrict__ rois,
    const int* __restrict__ roi_idx, float* __restrict__ out, int R)
{
    __shared__ __align__(16) uint2 plane[STRIDE * HH];  // 25984 B
    __shared__ int    list[MAXROI];
    __shared__ unsigned short ys[MAXROI * 7];   // sy | ey<<8
    __shared__ unsigned short xs[MAXROI * 7];   // sx | ex<<8
    __shared__ int cnt;

    const int b  = blockIdx.x;
    const int s  = b & (SPLIT - 1);
    const int pq = b >> 2;             // n*64 + cquad   (SPLIT=4 -> >>2)
    const int n  = pq >> 6;
    const int c0 = (pq & 63) * 4;
    const int t  = threadIdx.x;

    // Deterministic ascending-r compaction (wave 0 only) -- identical list
    // order across sibling blocks (R4 lesson: atomicAdd order is not).
    if (t < 64) {
        int base = 0;
        #pragma unroll
        for (int k = 0; k < 4; ++k) {
            int r = k * 64 + t;
            bool match = (r < R) && (roi_idx[r] == n);
            unsigned long long mask = __ballot(match);
            int pos = base + __popcll(mask & ((1ULL << t) - 1ULL));
            if (match && pos < MAXROI) list[pos] = r;
            base += __popcll(mask);
        }
        if (t == 0) cnt = (base < MAXROI) ? base : MAXROI;
    }

    // Stage 4 planes packed-fp16: plane[y*58+x] = {pack(A,B), pack(C,D)}.
    // 784 pixel-quads, 14 quads/row (56%4==0) -> no quad spans a row.
    const float4* srcA = reinterpret_cast<const float4*>(images + (size_t)(n * CC + c0)     * PX);
    const float4* srcB = reinterpret_cast<const float4*>(images + (size_t)(n * CC + c0 + 1) * PX);
    const float4* srcC = reinterpret_cast<const float4*>(images + (size_t)(n * CC + c0 + 2) * PX);
    const float4* srcD = reinterpret_cast<const float4*>(images + (size_t)(n * CC + c0 + 3) * PX);
    #pragma unroll
    for (int k = 0; k < 4; ++k) {
        int idx = t + k * 256;
        if (idx < PX / 4) {
            float4 a = srcA[idx], bb = srcB[idx], cc = srcC[idx], dd = srcD[idx];
            const float* ap = &a.x; const float* bp = &bb.x;
            const float* cp = &cc.x; const float* dp = &dd.x;
            int y  = idx / 14;
            int x0 = (idx - y * 14) * 4;
            unsigned lo[4], hi[4];
            #pragma unroll
            for (int p = 0; p < 4; ++p) {
                half2_t l = { (_Float16)ap[p], (_Float16)bp[p] };
                half2_t h = { (_Float16)cp[p], (_Float16)dp[p] };
                lo[p] = __builtin_bit_cast(unsigned, l);
                hi[p] = __builtin_bit_cast(unsigned, h);
            }
            uint4* dst = reinterpret_cast<uint4*>(&plane[y * STRIDE + x0]);
            dst[0] = make_uint4(lo[0], hi[0], lo[1], hi[1]);
            dst[1] = make_uint4(lo[2], hi[2], lo[3], hi[3]);
        }
    }
    __syncthreads();   // covers list/cnt too

    const int count = cnt;

    // Per-ROI bin-edge tables (e = m*7 + i serves rows and cols).
    for (int e = t; e < count * 7; e += 256) {
        int m = e / 7, i = e - m * 7;
        int r = list[m];
        float4 rv = reinterpret_cast<const float4*>(rois)[r];
        int x1 = (int)floorf(rv.x * (float)WW);
        int y1 = (int)floorf(rv.y * (float)HH);
        int x2 = (int)ceilf (rv.z * (float)WW);
        int y2 = (int)ceilf (rv.w * (float)HH);
        int Hr = y2 - y1, Wr = x2 - x1;
        int sy = y1 + (i * Hr) / 7, ey = y1 + ((i + 1) * Hr + 6) / 7;
        int sx = x1 + (i * Wr) / 7, ex = x1 + ((i + 1) * Wr + 6) / 7;
        ys[m * 7 + i] = (unsigned short)(sy | (ey << 8));
        xs[m * 7 + i] = (unsigned short)(sx | (ex << 8));
    }
    __syncthreads();

    const int wv   = t >> 6;
    const int lane = t & 63;
    const int i = lane / 7;
    const int j = lane - i * 7;

    if (lane < OUTS * OUTS) {
        const half2_t NEG = { (_Float16)-65504.0f, (_Float16)-65504.0f };
        // (chunk s, wave wv) takes list positions m % 16 == s + 4*wv.
        for (int m = (wv << 2) + s; m < count; m += SPLIT * 4) {
            int r = list[m];
            int yse = ys[m * 7 + i];
            int xse = xs[m * 7 + j];
            int sy = yse & 255, ey = yse >> 8;
            int sx = xse & 255, ex = xse >> 8;

            half2_t a01 = NEG, a23 = NEG;

            // 2-row x 4-col clamped chunks: 8 independent ds_read_b64 per
            // step (ILP); duplicate clamped reads are identity under max.
            for (int y = sy; y < ey; y += 2) {
                const uint2* r0 = plane + y * STRIDE;
                const uint2* r1 = plane + min(y + 1, ey - 1) * STRIDE;
                for (int x = sx; x < ex; x += 4) {
                    int xb = min(x + 1, ex - 1);
                    int xc = min(x + 2, ex - 1);
                    int xd = min(x + 3, ex - 1);
                    uint2 v0 = r0[x], v1 = r0[xb], v2 = r0[xc], v3 = r0[xd];
                    uint2 w0 = r1[x], w1 = r1[xb], w2 = r1[xc], w3 = r1[xd];
                    a01 = __builtin_elementwise_max(a01, __builtin_bit_cast(half2_t, v0.x));
                    a23 = __builtin_elementwise_max(a23, __builtin_bit_cast(half2_t, v0.y));
                    a01 = __builtin_elementwise_max(a01, __builtin_bit_cast(half2_t, v1.x));
                    a23 = __builtin_elementwise_max(a23, __builtin_bit_cast(half2_t, v1.y));
                    a01 = __builtin_elementwise_max(a01, __builtin_bit_cast(half2_t, v2.x));
                    a23 = __builtin_elementwise_max(a23, __builtin_bit_cast(half2_t, v2.y));
                    a01 = __builtin_elementwise_max(a01, __builtin_bit_cast(half2_t, v3.x));
                    a23 = __builtin_elementwise_max(a23, __builtin_bit_cast(half2_t, v3.y));
                    a01 = __builtin_elementwise_max(a01, __builtin_bit_cast(half2_t, w0.x));
                    a23 = __builtin_elementwise_max(a23, __builtin_bit_cast(half2_t, w0.y));
                    a01 = __builtin_elementwise_max(a01, __builtin_bit_cast(half2_t, w1.x));
                    a23 = __builtin_elementwise_max(a23, __builtin_bit_cast(half2_t, w1.y));
                    a01 = __builtin_elementwise_max(a01, __builtin_bit_cast(half2_t, w2.x));
                    a23 = __builtin_elementwise_max(a23, __builtin_bit_cast(half2_t, w2.y));
                    a01 = __builtin_elementwise_max(a01, __builtin_bit_cast(half2_t, w3.x));
                    a23 = __builtin_elementwise_max(a23, __builtin_bit_cast(half2_t, w3.y));
                }
            }

            // Unpack fp16 -> f32. Degenerate bins (Wr*Hr==0 edge case) get
            // exact finfo(f32).min to match the reference.
            bool ok = (ey > sy) && (ex > sx);
            const float NF = -3.402823466e+38f;
            float f0 = ok ? (float)a01.x : NF;
            float f1 = ok ? (float)a01.y : NF;
            float f2 = ok ? (float)a23.x : NF;
            float f3 = ok ? (float)a23.y : NF;

            size_t o = ((size_t)r * CC + c0) * (OUTS * OUTS) + lane;
            out[o]       = f0;
            out[o + 49]  = f1;
            out[o + 98]  = f2;
            out[o + 147] = f3;
        }
    }
}

extern "C" void kernel_launch(void* const* d_in, const int* in_sizes, int n_in,
                              void* d_out, int out_size, void* d_ws, size_t ws_size,
                              hipStream_t stream) {
    const float* images  = (const float*)d_in[0];
    const float* rois    = (const float*)d_in[1];
    const int*   roi_idx = (const int*)d_in[2];
    float* out = (float*)d_out;

    int R = in_sizes[2];                         // 256
    int N = in_sizes[0] / (CC * PX);             // 8

    int grid = N * (CC / 4) * SPLIT;             // 2048 blocks
    roipool_kernel<<<grid, 256, 0, stream>>>(images, rois, roi_idx, out, R);
}

// Round 2
// 87.386 us; speedup vs baseline: 1.0625x; 1.0625x over previous
//
#include <hip/hip_runtime.h>

#define OUTS 7
#define CC 256
#define HH 56
#define WW 56
#define PX (HH * WW)   // 3136
#define STRIDE 58      // px row stride (even: keeps 16B staging alignment)
#define SPLIT 1        // R12: single staging pass per plane (R11 measured ~2.7us/pass)
#define MAXROI 96

typedef _Float16 half2_t __attribute__((ext_vector_type(2)));  // trivially copyable

// R12: same R8/R10 structure (LDS-staged packed-fp16 plane, lane=bin,
// chunked-ILP scan, deterministic ROI list), SPLIT 2 -> 1.
// R11 post-mortem: SPLIT 2->4 cost +5.4us => each full-image staging pass
// costs ~2.7us and the kernel is staging-throughput-bound, not
// latency/occupancy-bound (extra TLP bought nothing). So stage each
// (n,cquad) plane exactly ONCE: grid 512 blocks (2/CU, 8 waves/CU), total
// global reads 25.7 MB (compulsory) instead of 51.4 MB. Scan work per CU
// is SPLIT-invariant (each wave now owns ~8 ROIs instead of ~4; same
// aggregate LDS-pipe throughput). Sibling-duplicate compaction + bin-table
// work also removed.
__global__ __launch_bounds__(256) void roipool_kernel(
    const float* __restrict__ images, const float* __restrict__ rois,
    const int* __restrict__ roi_idx, float* __restrict__ out, int R)
{
    __shared__ __align__(16) uint2 plane[STRIDE * HH];  // 25984 B
    __shared__ int    list[MAXROI];
    __shared__ unsigned short ys[MAXROI * 7];   // sy | ey<<8
    __shared__ unsigned short xs[MAXROI * 7];   // sx | ex<<8
    __shared__ int cnt;

    const int b  = blockIdx.x;
    const int s  = 0;                  // SPLIT=1: no sibling split
    const int pq = b;                  // n*64 + cquad
    const int n  = pq >> 6;
    const int c0 = (pq & 63) * 4;
    const int t  = threadIdx.x;

    // Deterministic ascending-r compaction (wave 0 only) -- identical list
    // order across blocks (R4 lesson: atomicAdd order is not).
    if (t < 64) {
        int base = 0;
        #pragma unroll
        for (int k = 0; k < 4; ++k) {
            int r = k * 64 + t;
            bool match = (r < R) && (roi_idx[r] == n);
            unsigned long long mask = __ballot(match);
            int pos = base + __popcll(mask & ((1ULL << t) - 1ULL));
            if (match && pos < MAXROI) list[pos] = r;
            base += __popcll(mask);
        }
        if (t == 0) cnt = (base < MAXROI) ? base : MAXROI;
    }

    // Stage 4 planes packed-fp16: plane[y*58+x] = {pack(A,B), pack(C,D)}.
    // 784 pixel-quads, 14 quads/row (56%4==0) -> no quad spans a row.
    const float4* srcA = reinterpret_cast<const float4*>(images + (size_t)(n * CC + c0)     * PX);
    const float4* srcB = reinterpret_cast<const float4*>(images + (size_t)(n * CC + c0 + 1) * PX);
    const float4* srcC = reinterpret_cast<const float4*>(images + (size_t)(n * CC + c0 + 2) * PX);
    const float4* srcD = reinterpret_cast<const float4*>(images + (size_t)(n * CC + c0 + 3) * PX);
    #pragma unroll
    for (int k = 0; k < 4; ++k) {
        int idx = t + k * 256;
        if (idx < PX / 4) {
            float4 a = srcA[idx], bb = srcB[idx], cc = srcC[idx], dd = srcD[idx];
            const float* ap = &a.x; const float* bp = &bb.x;
            const float* cp = &cc.x; const float* dp = &dd.x;
            int y  = idx / 14;
            int x0 = (idx - y * 14) * 4;
            unsigned lo[4], hi[4];
            #pragma unroll
            for (int p = 0; p < 4; ++p) {
                half2_t l = { (_Float16)ap[p], (_Float16)bp[p] };
                half2_t h = { (_Float16)cp[p], (_Float16)dp[p] };
                lo[p] = __builtin_bit_cast(unsigned, l);
                hi[p] = __builtin_bit_cast(unsigned, h);
            }
            uint4* dst = reinterpret_cast<uint4*>(&plane[y * STRIDE + x0]);
            dst[0] = make_uint4(lo[0], hi[0], lo[1], hi[1]);
            dst[1] = make_uint4(lo[2], hi[2], lo[3], hi[3]);
        }
    }
    __syncthreads();   // covers list/cnt too

    const int count = cnt;

    // Per-ROI bin-edge tables (e = m*7 + i serves rows and cols).
    for (int e = t; e < count * 7; e += 256) {
        int m = e / 7, i = e - m * 7;
        int r = list[m];
        float4 rv = reinterpret_cast<const float4*>(rois)[r];
        int x1 = (int)floorf(rv.x * (float)WW);
        int y1 = (int)floorf(rv.y * (float)HH);
        int x2 = (int)ceilf (rv.z * (float)WW);
        int y2 = (int)ceilf (rv.w * (float)HH);
        int Hr = y2 - y1, Wr = x2 - x1;
        int sy = y1 + (i * Hr) / 7, ey = y1 + ((i + 1) * Hr + 6) / 7;
        int sx = x1 + (i * Wr) / 7, ex = x1 + ((i + 1) * Wr + 6) / 7;
        ys[m * 7 + i] = (unsigned short)(sy | (ey << 8));
        xs[m * 7 + i] = (unsigned short)(sx | (ex << 8));
    }
    __syncthreads();

    const int wv   = t >> 6;
    const int lane = t & 63;
    const int i = lane / 7;
    const int j = lane - i * 7;

    if (lane < OUTS * OUTS) {
        const half2_t NEG = { (_Float16)-65504.0f, (_Float16)-65504.0f };
        // wave wv takes list positions m % 4 == wv.
        for (int m = wv + s; m < count; m += SPLIT * 4) {
            int r = list[m];
            int yse = ys[m * 7 + i];
            int xse = xs[m * 7 + j];
            int sy = yse & 255, ey = yse >> 8;
            int sx = xse & 255, ex = xse >> 8;

            half2_t a01 = NEG, a23 = NEG;

            // 2-row x 4-col clamped chunks: 8 independent ds_read_b64 per
            // step (ILP); duplicate clamped reads are identity under max.
            for (int y = sy; y < ey; y += 2) {
                const uint2* r0 = plane + y * STRIDE;
                const uint2* r1 = plane + min(y + 1, ey - 1) * STRIDE;
                for (int x = sx; x < ex; x += 4) {
                    int xb = min(x + 1, ex - 1);
                    int xc = min(x + 2, ex - 1);
                    int xd = min(x + 3, ex - 1);
                    uint2 v0 = r0[x], v1 = r0[xb], v2 = r0[xc], v3 = r0[xd];
                    uint2 w0 = r1[x], w1 = r1[xb], w2 = r1[xc], w3 = r1[xd];
                    a01 = __builtin_elementwise_max(a01, __builtin_bit_cast(half2_t, v0.x));
                    a23 = __builtin_elementwise_max(a23, __builtin_bit_cast(half2_t, v0.y));
                    a01 = __builtin_elementwise_max(a01, __builtin_bit_cast(half2_t, v1.x));
                    a23 = __builtin_elementwise_max(a23, __builtin_bit_cast(half2_t, v1.y));
                    a01 = __builtin_elementwise_max(a01, __builtin_bit_cast(half2_t, v2.x));
                    a23 = __builtin_elementwise_max(a23, __builtin_bit_cast(half2_t, v2.y));
                    a01 = __builtin_elementwise_max(a01, __builtin_bit_cast(half2_t, v3.x));
                    a23 = __builtin_elementwise_max(a23, __builtin_bit_cast(half2_t, v3.y));
                    a01 = __builtin_elementwise_max(a01, __builtin_bit_cast(half2_t, w0.x));
                    a23 = __builtin_elementwise_max(a23, __builtin_bit_cast(half2_t, w0.y));
                    a01 = __builtin_elementwise_max(a01, __builtin_bit_cast(half2_t, w1.x));
                    a23 = __builtin_elementwise_max(a23, __builtin_bit_cast(half2_t, w1.y));
                    a01 = __builtin_elementwise_max(a01, __builtin_bit_cast(half2_t, w2.x));
                    a23 = __builtin_elementwise_max(a23, __builtin_bit_cast(half2_t, w2.y));
                    a01 = __builtin_elementwise_max(a01, __builtin_bit_cast(half2_t, w3.x));
                    a23 = __builtin_elementwise_max(a23, __builtin_bit_cast(half2_t, w3.y));
                }
            }

            // Unpack fp16 -> f32. Degenerate bins (Wr*Hr==0 edge case) get
            // exact finfo(f32).min to match the reference.
            bool ok = (ey > sy) && (ex > sx);
            const float NF = -3.402823466e+38f;
            float f0 = ok ? (float)a01.x : NF;
            float f1 = ok ? (float)a01.y : NF;
            float f2 = ok ? (float)a23.x : NF;
            float f3 = ok ? (float)a23.y : NF;

            size_t o = ((size_t)r * CC + c0) * (OUTS * OUTS) + lane;
            out[o]       = f0;
            out[o + 49]  = f1;
            out[o + 98]  = f2;
            out[o + 147] = f3;
        }
    }
}

extern "C" void kernel_launch(void* const* d_in, const int* in_sizes, int n_in,
                              void* d_out, int out_size, void* d_ws, size_t ws_size,
                              hipStream_t stream) {
    const float* images  = (const float*)d_in[0];
    const float* rois    = (const float*)d_in[1];
    const int*   roi_idx = (const int*)d_in[2];
    float* out = (float*)d_out;

    int R = in_sizes[2];                         // 256
    int N = in_sizes[0] / (CC * PX);             // 8

    int grid = N * (CC / 4) * SPLIT;             // 512 blocks
    roipool_kernel<<<grid, 256, 0, stream>>>(images, rois, roi_idx, out, R);
}

// Round 3
// 86.316 us; speedup vs baseline: 1.0757x; 1.0124x over previous
//
#include <hip/hip_runtime.h>

#define OUTS 7
#define CC 256
#define HH 56
#define WW 56
#define PX (HH * WW)   // 3136
#define STRIDE8 57     // uint4 pixels per LDS row (odd: spreads banks)
#define SPLIT 2        // ROI-list split across sibling blocks
#define MAXROI 96

typedef _Float16 half2_t __attribute__((ext_vector_type(2)));  // trivially copyable

__device__ __forceinline__ unsigned packh2(float a, float b) {
    half2_t h = { (_Float16)a, (_Float16)b };
    return __builtin_bit_cast(unsigned, h);
}

// R13: scan-phase attack (the only never-ablated phase; R12 proved staging
// is off the critical path at SPLIT<=2). Pack 8 channels/pixel into one
// uint4 (16B): scan reads become ds_read_b128 (better B/cyc than b64, m134)
// and a 2-row x 2-col step covers the same 32 channel-pixels that R8's
// 2x4 b64 chunking needed 8 reads for, with lower clamp over-read on the
// typical ~3x3-px bin. Grid = N * (C/8) * SPLIT = 512 blocks (2/CU, 8
// waves/CU -- same occupancy as the 87.4us config). LDS 54 KB < 64 KB max.
// Discriminator: if dur doesn't move, kernel is under the harness floor.
__global__ __launch_bounds__(256) void roipool_kernel(
    const float* __restrict__ images, const float* __restrict__ rois,
    const int* __restrict__ roi_idx, float* __restrict__ out, int R)
{
    __shared__ __align__(16) uint4 plane[STRIDE8 * HH];  // 51072 B
    __shared__ int    list[MAXROI];
    __shared__ unsigned short ys[MAXROI * 7];   // sy | ey<<8
    __shared__ unsigned short xs[MAXROI * 7];   // sx | ex<<8
    __shared__ int cnt;

    const int b  = blockIdx.x;
    const int s  = b & (SPLIT - 1);
    const int pq = b >> 1;             // n*32 + c-octet
    const int n  = pq >> 5;
    const int c0 = (pq & 31) * 8;
    const int t  = threadIdx.x;

    // Deterministic ascending-r compaction (wave 0 only) -- identical list
    // order across sibling blocks (R4 lesson: atomicAdd order is not).
    if (t < 64) {
        int base = 0;
        #pragma unroll
        for (int k = 0; k < 4; ++k) {
            int r = k * 64 + t;
            bool match = (r < R) && (roi_idx[r] == n);
            unsigned long long mask = __ballot(match);
            int pos = base + __popcll(mask & ((1ULL << t) - 1ULL));
            if (match && pos < MAXROI) list[pos] = r;
            base += __popcll(mask);
        }
        if (t == 0) cnt = (base < MAXROI) ? base : MAXROI;
    }

    // Stage 8 planes packed-fp16: plane[y*57+x] = {h2(c0,c1),h2(c2,c3),
    // h2(c4,c5),h2(c6,c7)}. 784 pixel-quads, 14 quads/row -> no row spans.
    const float* base8 = images + (size_t)(n * CC + c0) * PX;
    #pragma unroll
    for (int k = 0; k < 4; ++k) {
        int idx = t + k * 256;
        if (idx < PX / 4) {
            float4 v[8];
            #pragma unroll
            for (int p = 0; p < 8; ++p)
                v[p] = reinterpret_cast<const float4*>(base8 + (size_t)p * PX)[idx];
            int y  = idx / 14;
            int x0 = (idx - y * 14) * 4;
            uint4* dst = &plane[y * STRIDE8 + x0];
            #pragma unroll
            for (int q = 0; q < 4; ++q) {
                const float f0 = ((const float*)&v[0])[q];
                const float f1 = ((const float*)&v[1])[q];
                const float f2 = ((const float*)&v[2])[q];
                const float f3 = ((const float*)&v[3])[q];
                const float f4 = ((const float*)&v[4])[q];
                const float f5 = ((const float*)&v[5])[q];
                const float f6 = ((const float*)&v[6])[q];
                const float f7 = ((const float*)&v[7])[q];
                dst[q] = make_uint4(packh2(f0, f1), packh2(f2, f3),
                                    packh2(f4, f5), packh2(f6, f7));
            }
        }
    }
    __syncthreads();   // covers list/cnt too

    const int count = cnt;

    // Per-ROI bin-edge tables (e = m*7 + i serves rows and cols).
    for (int e = t; e < count * 7; e += 256) {
        int m = e / 7, i = e - m * 7;
        int r = list[m];
        float4 rv = reinterpret_cast<const float4*>(rois)[r];
        int x1 = (int)floorf(rv.x * (float)WW);
        int y1 = (int)floorf(rv.y * (float)HH);
        int x2 = (int)ceilf (rv.z * (float)WW);
        int y2 = (int)ceilf (rv.w * (float)HH);
        int Hr = y2 - y1, Wr = x2 - x1;
        int sy = y1 + (i * Hr) / 7, ey = y1 + ((i + 1) * Hr + 6) / 7;
        int sx = x1 + (i * Wr) / 7, ex = x1 + ((i + 1) * Wr + 6) / 7;
        ys[m * 7 + i] = (unsigned short)(sy | (ey << 8));
        xs[m * 7 + i] = (unsigned short)(sx | (ex << 8));
    }
    __syncthreads();

    const int wv   = t >> 6;
    const int lane = t & 63;
    const int i = lane / 7;
    const int j = lane - i * 7;

    if (lane < OUTS * OUTS) {
        const half2_t NEG = { (_Float16)-65504.0f, (_Float16)-65504.0f };
        // (chunk s, wave wv) takes list positions m % 8 == s + 2*wv.
        for (int m = (wv << 1) + s; m < count; m += SPLIT * 4) {
            int r = list[m];
            int yse = ys[m * 7 + i];
            int xse = xs[m * 7 + j];
            int sy = yse & 255, ey = yse >> 8;
            int sx = xse & 255, ex = xse >> 8;

            half2_t a01 = NEG, a23 = NEG, a45 = NEG, a67 = NEG;

            // 2-row x 2-col clamped steps: 4 independent ds_read_b128 per
            // step (ILP); duplicate clamped reads are identity under max.
            for (int y = sy; y < ey; y += 2) {
                const uint4* r0 = plane + y * STRIDE8;
                const uint4* r1 = plane + min(y + 1, ey - 1) * STRIDE8;
                for (int x = sx; x < ex; x += 2) {
                    int xb = min(x + 1, ex - 1);
                    uint4 v0 = r0[x], v1 = r0[xb];
                    uint4 w0 = r1[x], w1 = r1[xb];
                    a01 = __builtin_elementwise_max(a01, __builtin_bit_cast(half2_t, v0.x));
                    a23 = __builtin_elementwise_max(a23, __builtin_bit_cast(half2_t, v0.y));
                    a45 = __builtin_elementwise_max(a45, __builtin_bit_cast(half2_t, v0.z));
                    a67 = __builtin_elementwise_max(a67, __builtin_bit_cast(half2_t, v0.w));
                    a01 = __builtin_elementwise_max(a01, __builtin_bit_cast(half2_t, v1.x));
                    a23 = __builtin_elementwise_max(a23, __builtin_bit_cast(half2_t, v1.y));
                    a45 = __builtin_elementwise_max(a45, __builtin_bit_cast(half2_t, v1.z));
                    a67 = __builtin_elementwise_max(a67, __builtin_bit_cast(half2_t, v1.w));
                    a01 = __builtin_elementwise_max(a01, __builtin_bit_cast(half2_t, w0.x));
                    a23 = __builtin_elementwise_max(a23, __builtin_bit_cast(half2_t, w0.y));
                    a45 = __builtin_elementwise_max(a45, __builtin_bit_cast(half2_t, w0.z));
                    a67 = __builtin_elementwise_max(a67, __builtin_bit_cast(half2_t, w0.w));
                    a01 = __builtin_elementwise_max(a01, __builtin_bit_cast(half2_t, w1.x));
                    a23 = __builtin_elementwise_max(a23, __builtin_bit_cast(half2_t, w1.y));
                    a45 = __builtin_elementwise_max(a45, __builtin_bit_cast(half2_t, w1.z));
                    a67 = __builtin_elementwise_max(a67, __builtin_bit_cast(half2_t, w1.w));
                }
            }

            // Unpack fp16 -> f32. Degenerate bins (Wr*Hr==0 edge case) get
            // exact finfo(f32).min to match the reference.
            bool ok = (ey > sy) && (ex > sx);
            const float NF = -3.402823466e+38f;
            float f0 = ok ? (float)a01.x : NF;
            float f1 = ok ? (float)a01.y : NF;
            float f2 = ok ? (float)a23.x : NF;
            float f3 = ok ? (float)a23.y : NF;
            float f4 = ok ? (float)a45.x : NF;
            float f5 = ok ? (float)a45.y : NF;
            float f6 = ok ? (float)a67.x : NF;
            float f7 = ok ? (float)a67.y : NF;

            size_t o = ((size_t)r * CC + c0) * (OUTS * OUTS) + lane;
            out[o]            = f0;
            out[o + 49]       = f1;
            out[o + 49 * 2]   = f2;
            out[o + 49 * 3]   = f3;
            out[o + 49 * 4]   = f4;
            out[o + 49 * 5]   = f5;
            out[o + 49 * 6]   = f6;
            out[o + 49 * 7]   = f7;
        }
    }
}

extern "C" void kernel_launch(void* const* d_in, const int* in_sizes, int n_in,
                              void* d_out, int out_size, void* d_ws, size_t ws_size,
                              hipStream_t stream) {
    const float* images  = (const float*)d_in[0];
    const float* rois    = (const float*)d_in[1];
    const int*   roi_idx = (const int*)d_in[2];
    float* out = (float*)d_out;

    int R = in_sizes[2];                         // 256
    int N = in_sizes[0] / (CC * PX);             // 8

    int grid = N * (CC / 8) * SPLIT;             // 512 blocks
    roipool_kernel<<<grid, 256, 0, stream>>>(images, rois, roi_idx, out, R);
}